// Round 7
// baseline (135.604 us; speedup 1.0000x reference)
//
#include <hip/hip_runtime.h>
#include <hip/hip_bf16.h>
#include <math.h>

// KoLeo loss, MI355X. Fused normalize -> bf16 fragment repack -> MFMA gram
// row-max (never materializes the 16384^2 gram) -> log/mean epilogue.
//
// v7: BARRIER-FREE reg-staged symmetric kmax. No LDS, no __syncthreads.
// Each wave independently walks a run of triangular units (64 i-rows x 32
// j-rows x K=256): i-fragments hoisted (128 VGPR), j-fragments streamed into
// a single 64-VGPR af buffer, prefetched for unit s+1 while unit s's epilogue
// VALU runs. Waves desync -> MFMA/VALU/VMEM pipes overlap across the CU's 8
// waves instead of phase-serializing behind barriers.
//   - i-side row-max kept in 2 regs, flushed by global atomicMax on fkey
//   - j-side col-max: in-place jm, then log-fold (DPP ror 8/4/2/1, register
//     halving; ror(+d)==xor(d) under symmetry of prior folds), cross-half
//     shfl_xor(16), one predicated global atomicMax per lane-half
//
// F layout (32-row tiles): chunk(t32,ks,lane) = t32*1024 + ks*64 + lane,
//   16B chunk = 8 bf16 of xn[t32*32 + (lane&31)][ks*16 + (lane>>5)*8 .. +7].
// == mfma_f32_32x32x16_bf16 A/B fragment layout -> coalesced 16B/lane loads.

typedef __attribute__((ext_vector_type(8))) short bf16x8;    // 8 bf16 = 4 VGPR
typedef __attribute__((ext_vector_type(16))) float f32x16;   // 32x32 acc

#define NROWS 16384
#define NDIM  256
#define NBLK  512            // 512 blocks x 4 waves = 2048 waves
#define NWAVE 2048
#define WUNITS 65792         // sum over B<256 of (512 - 2B)

// ---------------- K0: row 1/norm ----------------
__global__ __launch_bounds__(256) void knorm(const float* __restrict__ x,
                                             float* __restrict__ rn) {
    int wid = threadIdx.x >> 6, lane = threadIdx.x & 63;
    int row = blockIdx.x * 4 + wid;
    const float4* xr = (const float4*)(x + (size_t)row * NDIM);
    float4 v = xr[lane];
    float ss = v.x * v.x + v.y * v.y + v.z * v.z + v.w * v.w;
    #pragma unroll
    for (int m = 1; m < 64; m <<= 1) ss += __shfl_xor(ss, m, 64);
    if (lane == 0) rn[row] = 1.0f / fmaxf(sqrtf(ss), 1e-12f);
}

// ---------------- K1: normalize + pack to 32x32 fragment layout -----------
__device__ inline unsigned bf_rne(float f) {
    union { float f; unsigned u; } c; c.f = f;
    return (c.u + 0x7FFFu + ((c.u >> 16) & 1u)) >> 16;
}
__device__ inline unsigned pack2(float lo, float hi) {
    return bf_rne(lo) | (bf_rne(hi) << 16);
}

__global__ __launch_bounds__(256) void kpack(const float* __restrict__ x,
                                             const float* __restrict__ rn,
                                             uint4* __restrict__ F) {
    int g = blockIdx.x * 256 + threadIdx.x;
    int t32  = g >> 10;
    int rem  = g & 1023;
    int ks   = rem >> 6;
    int lane = rem & 63;
    int row  = t32 * 32 + (lane & 31);
    int kb   = ks * 16 + (lane >> 5) * 8;
    float s = rn[row];
    const float4* xr = (const float4*)(x + (size_t)row * NDIM + kb);
    float4 a = xr[0], b = xr[1];
    uint4 o;
    o.x = pack2(a.x * s, a.y * s);
    o.y = pack2(a.z * s, a.w * s);
    o.z = pack2(b.x * s, b.y * s);
    o.w = pack2(b.z * s, b.w * s);
    F[g] = o;
}

// ---------------- helpers ----------------
// monotone float->uint key (order-preserving); inverse in kloss1
__device__ inline unsigned fkey(float f) {
    unsigned u = __builtin_bit_cast(unsigned, f);
    return (u & 0x80000000u) ? ~u : (u | 0x80000000u);
}

template<int CTRL>                                  // plain DPP rotate (16-lane row)
__device__ inline float dpp_rot(float x) {
    int xi = __builtin_bit_cast(int, x);
    int yi = __builtin_amdgcn_update_dpp(xi, xi, CTRL, 0xF, 0xF, false);
    return __builtin_bit_cast(float, yi);
}

// ---------------- K2: barrier-free symmetric gram + two-sided max ---------
// 512 blocks x 256 threads (4 waves). Wave-unit = 64 i-rows x 32 j-rows.
__global__ __launch_bounds__(256, 2) void kmax(const bf16x8* __restrict__ F,
                                               unsigned* __restrict__ rowcand) {
    const int tid  = threadIdx.x;
    const int wid  = tid >> 6;
    const int lane = tid & 63;
    const int L    = lane & 31;
    const int hi   = lane >> 5;
    const int idx  = lane & 15;

    // XCD-chunked bijective swizzle (512 % 8 == 0): adjacent runs -> same XCD
    const int b = ((blockIdx.x & 7) << 6) | (blockIdx.x >> 3);
    const int g = b * 4 + wid;                      // global wave id
    // wave-run: [g*257/8, (g+1)*257/8)  (WUNITS/NWAVE = 32.125 = 257/8)
    const int u0   = (g * 257) >> 3;
    const int uend = ((g + 1) * 257) >> 3;

    // unit u -> (B, jt): prefix(B) = B*(513-B); jt = 2B + (u - prefix)
    int cib = 0;
    while ((cib + 1) * (513 - (cib + 1)) <= u0) ++cib;
    int jt = 2 * cib + (u0 - cib * (513 - cib));

    // i-side fragments: itiles {2cib, 2cib+1}, 16 ks x 4 VGPR each = 128 VGPR
    bf16x8 bfr0[16], bfr1[16];
    #pragma unroll
    for (int ks = 0; ks < 16; ++ks) {
        bfr0[ks] = F[(2 * cib + 0) * 1024 + ks * 64 + lane];
        bfr1[ks] = F[(2 * cib + 1) * 1024 + ks * 64 + lane];
    }
    // j-side fragment buffer for the first unit
    bf16x8 af[16];
    #pragma unroll
    for (int ks = 0; ks < 16; ++ks) af[ks] = F[jt * 1024 + ks * 64 + lane];

    float rmax0 = -1e30f, rmax1 = -1e30f;
    // diag in 32x32 C: col=lane&31 -> i; row=(r&3)+8*(r>>2)+4*hi -> j
    const bool dvalid = (((L >> 2) & 1) == hi);
    const int  dreg   = (L & 3) | ((L >> 3) << 2);
    const int  jloc   = (idx & 3) + 8 * (idx >> 2) + 4 * hi; // fold output j

    for (int s = u0; s < uend; ++s) {
        // ---- MFMA phase: 2 chains (x2 waves/SIMD = 4 chains = full pipe) --
        f32x16 c0 = {0.f}, c1 = {0.f};
        #pragma unroll
        for (int ks = 0; ks < 16; ++ks) {
            c0 = __builtin_amdgcn_mfma_f32_32x32x16_bf16(af[ks], bfr0[ks], c0, 0, 0, 0);
            c1 = __builtin_amdgcn_mfma_f32_32x32x16_bf16(af[ks], bfr1[ks], c1, 0, 0, 0);
        }

        // ---- next-unit coords + af prefetch (covers L2 latency w/ epilogue)
        int nib = cib, njt = jt + 1;
        if (njt == 512) { nib = cib + 1; njt = 2 * nib; }
        if (s + 1 < uend) {
            int pjt = njt < 512 ? njt : 511;        // clamp (never used OOB)
            #pragma unroll
            for (int ks = 0; ks < 16; ++ks)
                af[ks] = F[pjt * 1024 + ks * 64 + lane];
        }

        // ---- epilogue: diag mask -> rmax + in-place jm ----
        const bool m0 = (jt == 2 * cib), m1 = (jt == 2 * cib + 1);
        #pragma unroll
        for (int r = 0; r < 16; ++r) {
            float v0 = c0[r], v1 = c1[r];
            if (m0 && dvalid && r == dreg) v0 = -1e30f;
            if (m1 && dvalid && r == dreg) v1 = -1e30f;
            rmax0 = fmaxf(rmax0, v0);
            rmax1 = fmaxf(rmax1, v1);
            c0[r] = fmaxf(v0, v1);                  // jm in place
        }
        // log-fold 16 regs -> 1 across the 16-lane row (ror == xor under
        // the symmetry established by earlier folds)
        float f8[8];
        #pragma unroll
        for (int r = 0; r < 8; ++r) {
            float t = (idx & 8) ? c0[r + 8] : c0[r];
            f8[r] = fmaxf(t, dpp_rot<0x128>(t));    // row_ror:8
        }
        float f4[4];
        #pragma unroll
        for (int r = 0; r < 4; ++r) {
            float t = (idx & 4) ? f8[r + 4] : f8[r];
            f4[r] = fmaxf(t, dpp_rot<0x124>(t));    // row_ror:4
        }
        float f2a = fmaxf((idx & 2) ? f4[2] : f4[0],
                          dpp_rot<0x122>((idx & 2) ? f4[2] : f4[0]));
        float f2b = fmaxf((idx & 2) ? f4[3] : f4[1],
                          dpp_rot<0x122>((idx & 2) ? f4[3] : f4[1]));
        float f1 = (idx & 1) ? f2b : f2a;
        f1 = fmaxf(f1, dpp_rot<0x121>(f1));         // row_ror:1
        // lane idx now holds col-max of acc-reg idx => j = jt*32 + jloc
        f1 = fmaxf(f1, __shfl_xor(f1, 16, 64));     // merge i-halves
        if (!(lane & 16))
            atomicMax(&rowcand[jt * 32 + jloc], fkey(f1));

        // ---- i-block transition ----
        if (nib != cib) {
            float t0 = fmaxf(rmax0, __shfl_xor(rmax0, 32, 64));
            float t1 = fmaxf(rmax1, __shfl_xor(rmax1, 32, 64));
            if (lane < 32) {
                atomicMax(&rowcand[cib * 64 + L],      fkey(t0));
                atomicMax(&rowcand[cib * 64 + 32 + L], fkey(t1));
            }
            rmax0 = rmax1 = -1e30f;
            if (s + 1 < uend && nib < 256) {
                #pragma unroll
                for (int ks = 0; ks < 16; ++ks) {
                    bfr0[ks] = F[(2 * nib + 0) * 1024 + ks * 64 + lane];
                    bfr1[ks] = F[(2 * nib + 1) * 1024 + ks * 64 + lane];
                }
            }
        }
        cib = nib; jt = njt;
    }

    // final i-side flush (fkey(-1e30) after a just-flushed transition is a
    // tiny key; atomicMax makes it harmless)
    if (cib < 256) {
        float t0 = fmaxf(rmax0, __shfl_xor(rmax0, 32, 64));
        float t1 = fmaxf(rmax1, __shfl_xor(rmax1, 32, 64));
        if (lane < 32) {
            atomicMax(&rowcand[cib * 64 + L],      fkey(t0));
            atomicMax(&rowcand[cib * 64 + 32 + L], fkey(t1));
        }
    }
}

// ---------------- K3: loss epilogue (2-stage, deterministic) --------------
__global__ __launch_bounds__(256) void kloss1(const unsigned* __restrict__ rowcand,
                                              float* __restrict__ partial) {
    int i = blockIdx.x * 256 + threadIdx.x;         // 64 blocks x 256
    unsigned k = rowcand[i];
    unsigned u = (k & 0x80000000u) ? (k ^ 0x80000000u) : ~k;
    float gv = __builtin_bit_cast(float, u);
    float d = sqrtf(fmaxf(2.f - 2.f * gv, 0.f));
    float acc = logf(d + 1e-8f);
    #pragma unroll
    for (int m = 1; m < 64; m <<= 1) acc += __shfl_xor(acc, m, 64);
    __shared__ float p[4];
    int wid = threadIdx.x >> 6, lane = threadIdx.x & 63;
    if (lane == 0) p[wid] = acc;
    __syncthreads();
    if (threadIdx.x == 0)
        partial[blockIdx.x] = (p[0] + p[1]) + (p[2] + p[3]);
}

__global__ __launch_bounds__(64) void kloss2(const float* __restrict__ partial,
                                             float* __restrict__ out) {
    float acc = partial[threadIdx.x];
    #pragma unroll
    for (int m = 1; m < 64; m <<= 1) acc += __shfl_xor(acc, m, 64);
    if (threadIdx.x == 0) out[0] = -acc / (float)NROWS;
}

extern "C" void kernel_launch(void* const* d_in, const int* in_sizes, int n_in,
                              void* d_out, int out_size, void* d_ws, size_t ws_size,
                              hipStream_t stream) {
    const float* x = (const float*)d_in[0];
    float* out = (float*)d_out;
    char* ws = (char*)d_ws;

    uint4*    F       = (uint4*)ws;                                 // 8 MiB
    float*    rn      = (float*)(ws + 8u * 1024u * 1024u);          // 64 KiB
    unsigned* rowcand = (unsigned*)(ws + 8u * 1024u * 1024u + 65536u); // 64 KiB
    float*    partial = (float*)(ws + 8u * 1024u * 1024u + 131072u);   // 256 B

    hipMemsetAsync(rowcand, 0, NROWS * sizeof(unsigned), stream);
    knorm<<<NROWS / 4, 256, 0, stream>>>(x, rn);
    kpack<<<(NROWS * NDIM / 8) / 256, 256, 0, stream>>>(x, rn, F);
    kmax <<<NBLK, 256, 0, stream>>>((const bf16x8*)F, rowcand);
    kloss1<<<64, 256, 0, stream>>>(rowcand, partial);
    kloss2<<<1, 64, 0, stream>>>(partial, out);
}

// Round 8
// 94.495 us; speedup vs baseline: 1.4350x; 1.4350x over previous
//
#include <hip/hip_runtime.h>
#include <hip/hip_bf16.h>
#include <math.h>

// KoLeo loss, MI355X. Fused normalize -> bf16 fragment repack -> MFMA gram
// row-max (never materializes the 16384^2 gram) -> log/mean epilogue.
//
// v8: shared-LDS symmetric walk (v5) with
//   (1) counted-vmcnt triple-buffer pipeline: stage unit s+2 each iter, raw
//       s_barrier preceded by asm s_waitcnt vmcnt(3) -- stage loads stay in
//       flight across barriers (no vmcnt(0) drain in the loop).
//   (2) operand swap mfma(bfr_i, af_j): streamed j on the LANE axis (cheap
//       per-unit flush: 32 fmax + shfl + 1 atomic), hoisted i on the REG axis
//       (rm[2][16] accumulated per unit, DPP-folded only at ib transitions).
//   (3) unit = 512i x 32j, 8448 units = exactly 33 per block x 256 blocks;
//       XCD-chunked swizzle keeps each run's j-walk on one XCD's L2.
//
// F layout (32-row tiles): chunk(t32,ks,lane) = t32*1024 + ks*64 + lane,
//   16B chunk = 8 bf16 of xn[t32*32 + (lane&31)][ks*16 + (lane>>5)*8 .. +7].
// == mfma_f32_32x32x16_bf16 A/B fragment layout -> linear coalesced staging.

typedef __attribute__((ext_vector_type(8))) short bf16x8;    // 8 bf16 = 4 VGPR
typedef __attribute__((ext_vector_type(16))) float f32x16;   // 32x32 acc

#define NROWS 16384
#define NDIM  256
#define NBLK  256
#define UNITS_PER 33     // 8448 total super-diagonal units / 256 blocks

// ---------------- K0: row 1/norm ----------------
__global__ __launch_bounds__(256) void knorm(const float* __restrict__ x,
                                             float* __restrict__ rn) {
    int wid = threadIdx.x >> 6, lane = threadIdx.x & 63;
    int row = blockIdx.x * 4 + wid;
    const float4* xr = (const float4*)(x + (size_t)row * NDIM);
    float4 v = xr[lane];
    float ss = v.x * v.x + v.y * v.y + v.z * v.z + v.w * v.w;
    #pragma unroll
    for (int m = 1; m < 64; m <<= 1) ss += __shfl_xor(ss, m, 64);
    if (lane == 0) rn[row] = 1.0f / fmaxf(sqrtf(ss), 1e-12f);
}

// ---------------- K1: normalize + pack to 32x32 fragment layout -----------
__device__ inline unsigned bf_rne(float f) {
    union { float f; unsigned u; } c; c.f = f;
    return (c.u + 0x7FFFu + ((c.u >> 16) & 1u)) >> 16;
}
__device__ inline unsigned pack2(float lo, float hi) {
    return bf_rne(lo) | (bf_rne(hi) << 16);
}

__global__ __launch_bounds__(256) void kpack(const float* __restrict__ x,
                                             const float* __restrict__ rn,
                                             uint4* __restrict__ F) {
    int g = blockIdx.x * 256 + threadIdx.x;
    int t32  = g >> 10;
    int rem  = g & 1023;
    int ks   = rem >> 6;
    int lane = rem & 63;
    int row  = t32 * 32 + (lane & 31);
    int kb   = ks * 16 + (lane >> 5) * 8;
    float s = rn[row];
    const float4* xr = (const float4*)(x + (size_t)row * NDIM + kb);
    float4 a = xr[0], b = xr[1];
    uint4 o;
    o.x = pack2(a.x * s, a.y * s);
    o.y = pack2(a.z * s, a.w * s);
    o.z = pack2(b.x * s, b.y * s);
    o.w = pack2(b.z * s, b.w * s);
    F[g] = o;
}

// ---------------- helpers ----------------
__device__ inline void stage16(const uint4* __restrict__ g, const uint4* l) {
    __builtin_amdgcn_global_load_lds(
        (const __attribute__((address_space(1))) unsigned*)g,
        (__attribute__((address_space(3))) unsigned*)l, 16, 0, 0);
}

// monotone float->uint key (order-preserving); inverse in kloss1
__device__ inline unsigned fkey(float f) {
    unsigned u = __builtin_bit_cast(unsigned, f);
    return (u & 0x80000000u) ? ~u : (u | 0x80000000u);
}

template<int CTRL>                                  // DPP rotate within 16-lane row
__device__ inline float dpp_rot(float x) {
    int xi = __builtin_bit_cast(int, x);
    int yi = __builtin_amdgcn_update_dpp(xi, xi, CTRL, 0xF, 0xF, false);
    return __builtin_bit_cast(float, yi);
}

// ---------------- K2: pipelined symmetric gram + two-sided max ------------
// 256 blocks x 512 threads (8 waves). Unit = 512 i-rows x 32 j-rows.
// D = mfma(bfr_t, af): col=lane&31 -> j_local, row=(r&3)+8(r>>2)+4(lane>>5) -> i_local.
__global__ __launch_bounds__(512, 2) void kmax(const bf16x8* __restrict__ F,
                                               unsigned* __restrict__ rowcand) {
    __shared__ uint4 sbuf[3][1024];                 // 3 x 16KB j-tile buffers
    __shared__ uint4 dump[64];                      // pad-load target (dead)

    const int tid  = threadIdx.x;
    const int wid  = tid >> 6;
    const int lane = tid & 63;
    const int L    = lane & 31;
    const int hi   = lane >> 5;
    const uint4* F4 = (const uint4*)F;

    // XCD-chunked bijective swizzle (256 % 8 == 0)
    const int b  = ((blockIdx.x & 7) << 5) | (blockIdx.x >> 3);
    const int u0 = b * UNITS_PER;

    // decode u0 -> (cib, cjt): prefix P(ib) = ib*(520-8ib); jt0(ib) = 16*ib
    int cib = 0;
    while ((cib + 1) * (520 - 8 * (cib + 1)) <= u0) ++cib;
    int cjt = 16 * cib + (u0 - cib * (520 - 8 * cib));

    // hoisted i-fragments: tiles {cib*16+wid*2, +1}, 128 VGPR
    int myit = cib * 16 + wid * 2;
    bf16x8 bfr0[16], bfr1[16];
    #pragma unroll
    for (int ks = 0; ks < 16; ++ks) {
        bfr0[ks] = F[(myit + 0) * 1024 + ks * 64 + lane];
        bfr1[ks] = F[(myit + 1) * 1024 + ks * 64 + lane];
    }

    auto stage_unit = [&](int jt, uint4* dst) {     // 2 loads per thread
        const uint4* gp = F4 + (size_t)jt * 1024;
        stage16(gp + tid,       dst + wid * 64);
        stage16(gp + 512 + tid, dst + 512 + wid * 64);
    };
    auto stepc = [](int& ib, int& jt) {
        if (++jt == 512) { if (ib < 31) { ++ib; jt = 16 * ib; } else jt = 511; }
    };

    // prologue: stage(u0), pad(1 load), stage(u0+1) -> 5 vmem ops; vmcnt(3)
    // at iter 0 then guarantees both stage(u0) loads retired.
    int sib = cib, sjt = cjt;
    stage_unit(sjt, sbuf[0]);
    stage16(F4 + tid, dump);
    stepc(sib, sjt);
    stage_unit(sjt, sbuf[1]);

    float rm0[16], rm1[16];
    #pragma unroll
    for (int r = 0; r < 16; ++r) { rm0[r] = -1e30f; rm1[r] = -1e30f; }

    const bool dvalid = (((L >> 2) & 1) == hi);     // lane holds a diag elem
    const int  dreg   = (L & 3) | ((L >> 3) << 2);  // ...at this acc reg

    // fold rm over j-lanes and flush i-side maxima for i-block fib
    auto flush_i = [&](int fib) {
        #pragma unroll
        for (int r = 0; r < 16; ++r) {
            float a = rm0[r];
            a = fmaxf(a, dpp_rot<0x121>(a));
            a = fmaxf(a, dpp_rot<0x122>(a));
            a = fmaxf(a, dpp_rot<0x124>(a));
            a = fmaxf(a, dpp_rot<0x128>(a));
            rm0[r] = fmaxf(a, __shfl_xor(a, 16, 64));
            float c = rm1[r];
            c = fmaxf(c, dpp_rot<0x121>(c));
            c = fmaxf(c, dpp_rot<0x122>(c));
            c = fmaxf(c, dpp_rot<0x124>(c));
            c = fmaxf(c, dpp_rot<0x128>(c));
            rm1[r] = fmaxf(c, __shfl_xor(c, 16, 64));
        }
        float v0 = rm0[0], v1 = rm1[0];
        #pragma unroll
        for (int r = 1; r < 16; ++r) {
            v0 = (dreg == r) ? rm0[r] : v0;         // lane L picks its i-row
            v1 = (dreg == r) ? rm1[r] : v1;
        }
        if (dvalid) {
            int base = fib * 512 + wid * 64;
            atomicMax(&rowcand[base + L],      fkey(v0));
            atomicMax(&rowcand[base + 32 + L], fkey(v1));
        }
    };

    int myib = cib;
    int bsel = 0;
    for (int s = 0; s < UNITS_PER; ++s) {
        // wait for stage(s) (all newer: 1 atomic + 2 loads of stage(s+1));
        // barrier makes every wave's stage visible before any wave reads.
        asm volatile("s_waitcnt vmcnt(3)" ::: "memory");
        __builtin_amdgcn_s_barrier();
        __builtin_amdgcn_sched_barrier(0);

        const uint4* sb = &sbuf[bsel][0];
        f32x16 c0 = {0.f}, c1 = {0.f};
        #pragma unroll
        for (int ks = 0; ks < 16; ++ks) {
            bf16x8 af = *(const bf16x8*)(sb + ks * 64 + lane);
            c0 = __builtin_amdgcn_mfma_f32_32x32x16_bf16(bfr0[ks], af, c0, 0, 0, 0);
            c1 = __builtin_amdgcn_mfma_f32_32x32x16_bf16(bfr1[ks], af, c1, 0, 0, 0);
        }

        // epilogue: diag mask -> j-flush (lane axis) + rm accumulate (reg axis)
        const bool m0 = (cjt == myit), m1 = (cjt == myit + 1);
        float jm = -1e30f;
        #pragma unroll
        for (int r = 0; r < 16; ++r) {
            float v0 = c0[r], v1 = c1[r];
            if (m0 && dvalid && r == dreg) v0 = -1e30f;
            if (m1 && dvalid && r == dreg) v1 = -1e30f;
            rm0[r] = fmaxf(rm0[r], v0);
            rm1[r] = fmaxf(rm1[r], v1);
            jm = fmaxf(jm, fmaxf(v0, v1));
        }
        jm = fmaxf(jm, __shfl_xor(jm, 32, 64));     // merge i-halves
        if (lane < 32) atomicMax(&rowcand[cjt * 32 + L], fkey(jm));

        // advance compute cursor; rare i-block transition
        stepc(cib, cjt);
        if (cib != myib) {
            flush_i(myib);
            #pragma unroll
            for (int r = 0; r < 16; ++r) { rm0[r] = -1e30f; rm1[r] = -1e30f; }
            myib = cib;
            if (s + 1 < UNITS_PER) {
                myit = cib * 16 + wid * 2;
                #pragma unroll
                for (int ks = 0; ks < 16; ++ks) {
                    bfr0[ks] = F[(myit + 0) * 1024 + ks * 64 + lane];
                    bfr1[ks] = F[(myit + 1) * 1024 + ks * 64 + lane];
                }
            }
        }

        // stage unit s+2 into slot (s+2)%3 (its old content: unit s-1, whose
        // readers all passed this iter's barrier). Tail: clamped re-stage of
        // the last unit into a dead slot (keeps vmcnt accounting uniform).
        __builtin_amdgcn_sched_barrier(0);
        stepc(sib, sjt);
        stage_unit(sjt, &sbuf[bsel + 2 >= 3 ? bsel - 1 : bsel + 2][0]);
        bsel = (bsel + 1 >= 3) ? 0 : bsel + 1;
    }
    flush_i(myib);
}

// ---------------- K3: loss epilogue (2-stage, deterministic) --------------
__global__ __launch_bounds__(256) void kloss1(const unsigned* __restrict__ rowcand,
                                              float* __restrict__ partial) {
    int i = blockIdx.x * 256 + threadIdx.x;         // 64 blocks x 256
    unsigned k = rowcand[i];
    unsigned u = (k & 0x80000000u) ? (k ^ 0x80000000u) : ~k;
    float gv = __builtin_bit_cast(float, u);
    float d = sqrtf(fmaxf(2.f - 2.f * gv, 0.f));
    float acc = logf(d + 1e-8f);
    #pragma unroll
    for (int m = 1; m < 64; m <<= 1) acc += __shfl_xor(acc, m, 64);
    __shared__ float p[4];
    int wid = threadIdx.x >> 6, lane = threadIdx.x & 63;
    if (lane == 0) p[wid] = acc;
    __syncthreads();
    if (threadIdx.x == 0)
        partial[blockIdx.x] = (p[0] + p[1]) + (p[2] + p[3]);
}

__global__ __launch_bounds__(64) void kloss2(const float* __restrict__ partial,
                                             float* __restrict__ out) {
    float acc = partial[threadIdx.x];
    #pragma unroll
    for (int m = 1; m < 64; m <<= 1) acc += __shfl_xor(acc, m, 64);
    if (threadIdx.x == 0) out[0] = -acc / (float)NROWS;
}

extern "C" void kernel_launch(void* const* d_in, const int* in_sizes, int n_in,
                              void* d_out, int out_size, void* d_ws, size_t ws_size,
                              hipStream_t stream) {
    const float* x = (const float*)d_in[0];
    float* out = (float*)d_out;
    char* ws = (char*)d_ws;

    uint4*    F       = (uint4*)ws;                                 // 8 MiB
    float*    rn      = (float*)(ws + 8u * 1024u * 1024u);          // 64 KiB
    unsigned* rowcand = (unsigned*)(ws + 8u * 1024u * 1024u + 65536u); // 64 KiB
    float*    partial = (float*)(ws + 8u * 1024u * 1024u + 131072u);   // 256 B

    hipMemsetAsync(rowcand, 0, NROWS * sizeof(unsigned), stream);
    knorm<<<NROWS / 4, 256, 0, stream>>>(x, rn);
    kpack<<<(NROWS * NDIM / 8) / 256, 256, 0, stream>>>(x, rn, F);
    kmax <<<NBLK, 512, 0, stream>>>((const bf16x8*)F, rowcand);
    kloss1<<<64, 256, 0, stream>>>(rowcand, partial);
    kloss2<<<1, 64, 0, stream>>>(partial, out);
}

// Round 9
// 93.470 us; speedup vs baseline: 1.4508x; 1.0110x over previous
//
#include <hip/hip_runtime.h>
#include <hip/hip_bf16.h>
#include <math.h>

// KoLeo loss, MI355X. Fused normalize -> bf16 fragment repack -> MFMA gram
// row-max (never materializes the 16384^2 gram) -> log/mean epilogue.
//
// v9: v8's counted-vmcnt symmetric walk, reshaped to 4-wave blocks (256 thr,
// 256-row i-panel, grid 512 = TWO blocks per CU). Independent block barriers
// desync -> one block's MFMA covers the other's epilogue VALU (m114 overlap);
// register/LDS budget now actually allows co-residency (R6 failed this).
// Plus: wave-uniform diag fast path (skips 32 cndmasks on non-diag units),
// split jm dep chains.
//
// F layout (32-row tiles): chunk(t32,ks,lane) = t32*1024 + ks*64 + lane,
//   16B chunk = 8 bf16 of xn[t32*32 + (lane&31)][ks*16 + (lane>>5)*8 .. +7].
// == mfma_f32_32x32x16_bf16 A/B fragment layout -> linear coalesced staging.

typedef __attribute__((ext_vector_type(8))) short bf16x8;    // 8 bf16 = 4 VGPR
typedef __attribute__((ext_vector_type(16))) float f32x16;   // 32x32 acc

#define NROWS 16384
#define NDIM  256
#define NBLK  512        // 512 blocks x 4 waves; 2 blocks/CU
// triangular units: unit = 256i x 32j; P(ib) = ib*(516-4ib); total 16640

// ---------------- K0: row 1/norm ----------------
__global__ __launch_bounds__(256) void knorm(const float* __restrict__ x,
                                             float* __restrict__ rn) {
    int wid = threadIdx.x >> 6, lane = threadIdx.x & 63;
    int row = blockIdx.x * 4 + wid;
    const float4* xr = (const float4*)(x + (size_t)row * NDIM);
    float4 v = xr[lane];
    float ss = v.x * v.x + v.y * v.y + v.z * v.z + v.w * v.w;
    #pragma unroll
    for (int m = 1; m < 64; m <<= 1) ss += __shfl_xor(ss, m, 64);
    if (lane == 0) rn[row] = 1.0f / fmaxf(sqrtf(ss), 1e-12f);
}

// ---------------- K1: normalize + pack to 32x32 fragment layout -----------
__device__ inline unsigned bf_rne(float f) {
    union { float f; unsigned u; } c; c.f = f;
    return (c.u + 0x7FFFu + ((c.u >> 16) & 1u)) >> 16;
}
__device__ inline unsigned pack2(float lo, float hi) {
    return bf_rne(lo) | (bf_rne(hi) << 16);
}

__global__ __launch_bounds__(256) void kpack(const float* __restrict__ x,
                                             const float* __restrict__ rn,
                                             uint4* __restrict__ F) {
    int g = blockIdx.x * 256 + threadIdx.x;
    int t32  = g >> 10;
    int rem  = g & 1023;
    int ks   = rem >> 6;
    int lane = rem & 63;
    int row  = t32 * 32 + (lane & 31);
    int kb   = ks * 16 + (lane >> 5) * 8;
    float s = rn[row];
    const float4* xr = (const float4*)(x + (size_t)row * NDIM + kb);
    float4 a = xr[0], b = xr[1];
    uint4 o;
    o.x = pack2(a.x * s, a.y * s);
    o.y = pack2(a.z * s, a.w * s);
    o.z = pack2(b.x * s, b.y * s);
    o.w = pack2(b.z * s, b.w * s);
    F[g] = o;
}

// ---------------- helpers ----------------
__device__ inline void stage16(const uint4* __restrict__ g, const uint4* l) {
    __builtin_amdgcn_global_load_lds(
        (const __attribute__((address_space(1))) unsigned*)g,
        (__attribute__((address_space(3))) unsigned*)l, 16, 0, 0);
}

// monotone float->uint key (order-preserving); inverse in kloss1
__device__ inline unsigned fkey(float f) {
    unsigned u = __builtin_bit_cast(unsigned, f);
    return (u & 0x80000000u) ? ~u : (u | 0x80000000u);
}

template<int CTRL>                                  // DPP rotate within 16-lane row
__device__ inline float dpp_rot(float x) {
    int xi = __builtin_bit_cast(int, x);
    int yi = __builtin_amdgcn_update_dpp(xi, xi, CTRL, 0xF, 0xF, false);
    return __builtin_bit_cast(float, yi);
}

// ---------------- K2: pipelined symmetric gram + two-sided max ------------
// 512 blocks x 256 threads (4 waves). Unit = 256 i-rows x 32 j-rows.
// D = mfma(bfr_i, af_j): col=lane&31 -> j_local, row=(r&3)+8(r>>2)+4(lane>>5) -> i_local.
__global__ __launch_bounds__(256, 2) void kmax(const bf16x8* __restrict__ F,
                                               unsigned* __restrict__ rowcand) {
    __shared__ uint4 sbuf[3][1024];                 // 3 x 16KB j-tile buffers
    __shared__ uint4 dump[64];                      // pad-load target (dead)

    const int tid  = threadIdx.x;
    const int wid  = tid >> 6;                      // 0..3
    const int lane = tid & 63;
    const int L    = lane & 31;
    const int hi   = lane >> 5;
    const uint4* F4 = (const uint4*)F;

    // XCD-chunked bijective swizzle (512 % 8 == 0)
    const int b  = ((blockIdx.x & 7) << 6) | (blockIdx.x >> 3);
    // run partition: 16640 units / 512 blocks = 32.5
    const int u0   = (b * 65) >> 1;
    const int uend = ((b + 1) * 65) >> 1;

    // decode u0 -> (cib, cjt): P(ib) = ib*(516-4ib); jt0(ib) = 8*ib
    int cib = 0;
    while ((cib + 1) * (516 - 4 * (cib + 1)) <= u0) ++cib;
    int cjt = 8 * cib + (u0 - cib * (516 - 4 * cib));

    // hoisted i-fragments: tiles {cib*8 + wid*2, +1}, 128 VGPR
    int myit = cib * 8 + wid * 2;
    bf16x8 bfr0[16], bfr1[16];
    #pragma unroll
    for (int ks = 0; ks < 16; ++ks) {
        bfr0[ks] = F[(myit + 0) * 1024 + ks * 64 + lane];
        bfr1[ks] = F[(myit + 1) * 1024 + ks * 64 + lane];
    }

    auto stage_unit = [&](int jt, uint4* dst) {     // 4 x 16B per thread
        const uint4* gp = F4 + (size_t)jt * 1024;
        #pragma unroll
        for (int q = 0; q < 4; ++q)
            stage16(gp + q * 256 + tid, dst + q * 256 + wid * 64);
    };
    auto stepc = [](int& ib, int& jt) {
        if (++jt == 512) { if (ib < 63) { ++ib; jt = 8 * ib; } else jt = 511; }
    };

    // prologue: stage(u0) [4], pad [1], stage(u0+1) [4] -> vmcnt(5) at iter 0
    // leaves exactly {pad? no: 1 pad + 4 of stage(u0+1)} = 5 newest -> stage(u0) drained.
    int sib = cib, sjt = cjt;
    stage_unit(sjt, sbuf[0]);
    stage16(F4 + tid, dump);
    stepc(sib, sjt);
    stage_unit(sjt, sbuf[1]);

    float rm0[16], rm1[16];
    #pragma unroll
    for (int r = 0; r < 16; ++r) { rm0[r] = -1e30f; rm1[r] = -1e30f; }

    const bool dvalid = (((L >> 2) & 1) == hi);     // lane holds a diag elem
    const int  dreg   = (L & 3) | ((L >> 3) << 2);  // ...at this acc reg

    // fold rm over j-lanes and flush i-side maxima for i-block fib
    auto flush_i = [&](int fib) {
        #pragma unroll
        for (int r = 0; r < 16; ++r) {
            float a = rm0[r];
            a = fmaxf(a, dpp_rot<0x121>(a));
            a = fmaxf(a, dpp_rot<0x122>(a));
            a = fmaxf(a, dpp_rot<0x124>(a));
            a = fmaxf(a, dpp_rot<0x128>(a));
            rm0[r] = fmaxf(a, __shfl_xor(a, 16, 64));
            float c = rm1[r];
            c = fmaxf(c, dpp_rot<0x121>(c));
            c = fmaxf(c, dpp_rot<0x122>(c));
            c = fmaxf(c, dpp_rot<0x124>(c));
            c = fmaxf(c, dpp_rot<0x128>(c));
            rm1[r] = fmaxf(c, __shfl_xor(c, 16, 64));
        }
        float v0 = rm0[0], v1 = rm1[0];
        #pragma unroll
        for (int r = 1; r < 16; ++r) {
            v0 = (dreg == r) ? rm0[r] : v0;         // lane picks its i-row
            v1 = (dreg == r) ? rm1[r] : v1;
        }
        if (dvalid) {
            int base = fib * 256 + wid * 64;
            atomicMax(&rowcand[base + L],      fkey(v0));
            atomicMax(&rowcand[base + 32 + L], fkey(v1));
        }
    };

    int myib = cib;
    int bsel = 0;
    for (int s = u0; s < uend; ++s) {
        // stage(s) guaranteed done: everything older than the newest 5 vmem
        // ops (1 j-atomic + 4 stage loads of s+1) has retired.
        asm volatile("s_waitcnt vmcnt(5)" ::: "memory");
        __builtin_amdgcn_s_barrier();
        __builtin_amdgcn_sched_barrier(0);

        const uint4* sb = &sbuf[bsel][0];
        f32x16 c0 = {0.f}, c1 = {0.f};
        #pragma unroll
        for (int ks = 0; ks < 16; ++ks) {
            bf16x8 af = *(const bf16x8*)(sb + ks * 64 + lane);
            c0 = __builtin_amdgcn_mfma_f32_32x32x16_bf16(bfr0[ks], af, c0, 0, 0, 0);
            c1 = __builtin_amdgcn_mfma_f32_32x32x16_bf16(bfr1[ks], af, c1, 0, 0, 0);
        }

        // epilogue: wave-uniform diag fast path; split jm dep chains
        float jma = -1e30f, jmb = -1e30f;
        if (cjt == myit || cjt == myit + 1) {       // rare: diag unit
            const bool m0 = (cjt == myit);
            #pragma unroll
            for (int r = 0; r < 16; ++r) {
                float v0 = c0[r], v1 = c1[r];
                if (m0 && dvalid && r == dreg)  v0 = -1e30f;
                if (!m0 && dvalid && r == dreg) v1 = -1e30f;
                rm0[r] = fmaxf(rm0[r], v0);
                rm1[r] = fmaxf(rm1[r], v1);
                if (r & 1) jmb = fmaxf(jmb, fmaxf(v0, v1));
                else       jma = fmaxf(jma, fmaxf(v0, v1));
            }
        } else {
            #pragma unroll
            for (int r = 0; r < 16; ++r) {
                float v0 = c0[r], v1 = c1[r];
                rm0[r] = fmaxf(rm0[r], v0);
                rm1[r] = fmaxf(rm1[r], v1);
                if (r & 1) jmb = fmaxf(jmb, fmaxf(v0, v1));
                else       jma = fmaxf(jma, fmaxf(v0, v1));
            }
        }
        float jm = fmaxf(jma, jmb);
        jm = fmaxf(jm, __shfl_xor(jm, 32, 64));     // merge i-halves
        if (lane < 32) atomicMax(&rowcand[cjt * 32 + L], fkey(jm));

        // advance compute cursor; rare i-block transition
        stepc(cib, cjt);
        if (cib != myib) {
            flush_i(myib);
            #pragma unroll
            for (int r = 0; r < 16; ++r) { rm0[r] = -1e30f; rm1[r] = -1e30f; }
            myib = cib;
            if (s + 1 < uend) {
                myit = cib * 8 + wid * 2;
                #pragma unroll
                for (int ks = 0; ks < 16; ++ks) {
                    bfr0[ks] = F[(myit + 0) * 1024 + ks * 64 + lane];
                    bfr1[ks] = F[(myit + 1) * 1024 + ks * 64 + lane];
                }
            }
        }

        // stage unit s+2 into the retiring slot (its readers passed the
        // barrier this iter). Tail: clamped re-stage (uniform vmcnt).
        __builtin_amdgcn_sched_barrier(0);
        stepc(sib, sjt);
        stage_unit(sjt, &sbuf[bsel + 2 >= 3 ? bsel - 1 : bsel + 2][0]);
        bsel = (bsel + 1 >= 3) ? 0 : bsel + 1;
    }
    flush_i(myib);
}

// ---------------- K3: loss epilogue (2-stage, deterministic) --------------
__global__ __launch_bounds__(256) void kloss1(const unsigned* __restrict__ rowcand,
                                              float* __restrict__ partial) {
    int i = blockIdx.x * 256 + threadIdx.x;         // 64 blocks x 256
    unsigned k = rowcand[i];
    unsigned u = (k & 0x80000000u) ? (k ^ 0x80000000u) : ~k;
    float gv = __builtin_bit_cast(float, u);
    float d = sqrtf(fmaxf(2.f - 2.f * gv, 0.f));
    float acc = logf(d + 1e-8f);
    #pragma unroll
    for (int m = 1; m < 64; m <<= 1) acc += __shfl_xor(acc, m, 64);
    __shared__ float p[4];
    int wid = threadIdx.x >> 6, lane = threadIdx.x & 63;
    if (lane == 0) p[wid] = acc;
    __syncthreads();
    if (threadIdx.x == 0)
        partial[blockIdx.x] = (p[0] + p[1]) + (p[2] + p[3]);
}

__global__ __launch_bounds__(64) void kloss2(const float* __restrict__ partial,
                                             float* __restrict__ out) {
    float acc = partial[threadIdx.x];
    #pragma unroll
    for (int m = 1; m < 64; m <<= 1) acc += __shfl_xor(acc, m, 64);
    if (threadIdx.x == 0) out[0] = -acc / (float)NROWS;
}

extern "C" void kernel_launch(void* const* d_in, const int* in_sizes, int n_in,
                              void* d_out, int out_size, void* d_ws, size_t ws_size,
                              hipStream_t stream) {
    const float* x = (const float*)d_in[0];
    float* out = (float*)d_out;
    char* ws = (char*)d_ws;

    uint4*    F       = (uint4*)ws;                                 // 8 MiB
    float*    rn      = (float*)(ws + 8u * 1024u * 1024u);          // 64 KiB
    unsigned* rowcand = (unsigned*)(ws + 8u * 1024u * 1024u + 65536u); // 64 KiB
    float*    partial = (float*)(ws + 8u * 1024u * 1024u + 131072u);   // 256 B

    hipMemsetAsync(rowcand, 0, NROWS * sizeof(unsigned), stream);
    knorm<<<NROWS / 4, 256, 0, stream>>>(x, rn);
    kpack<<<(NROWS * NDIM / 8) / 256, 256, 0, stream>>>(x, rn, F);
    kmax <<<NBLK, 256, 0, stream>>>((const bf16x8*)F, rowcand);
    kloss1<<<64, 256, 0, stream>>>(rowcand, partial);
    kloss2<<<1, 64, 0, stream>>>(partial, out);
}